// Round 8
// baseline (1581.769 us; speedup 1.0000x reference)
//
#include <hip/hip_runtime.h>
#include <hip/hip_bf16.h>
#include <cstdint>

#define B_ 2
#define C_ 128
#define E_ 60000

typedef unsigned int uint32_;

// load float via byte offset (keeps addressing as saddr + 32-bit voffset)
__device__ __forceinline__ float ldf(const float* p, uint32_ bo) {
    return *(const float*)((const char*)p + bo);
}

// ---------------------------------------------------------------------------
// Kernel 0: fold the 256->3 fuse conv into per-path weights (wave-parallel).
// NEW layout: Vw[c*32 + p*15 + j*5 + s]  (channel-major, 30 used + 2 pad) so
// the mesh kernel reads one channel's 30 weights with two s_load_dwordx16.
// s=0 absorbs the local conv. cst[j] = all bias terms. Grid = 16 blocks.
// ---------------------------------------------------------------------------
__global__ __launch_bounds__(256) void fuse_weights_kernel(
    const float* __restrict__ Wa_local, const float* __restrict__ ba_local,
    const float* __restrict__ Wb_local, const float* __restrict__ bb_local,
    const float* __restrict__ Wa_tri,  const float* __restrict__ ba_tri,
    const float* __restrict__ Wb_tri,  const float* __restrict__ bb_tri,
    const float* __restrict__ Wa_fuse, const float* __restrict__ ba_fuse,
    const float* __restrict__ Wb_fuse, const float* __restrict__ bb_fuse,
    float* __restrict__ Vw, float* __restrict__ cst)
{
    const int lane = threadIdx.x & 63;
    if (blockIdx.x < 15) {
        const int wid   = blockIdx.x * 4 + (threadIdx.x >> 6); // 0..59
        const int pj    = wid / 10;                            // 0..5
        const int chunk = wid % 10;                            // 0..9
        const int p = pj / 3, j = pj % 3;
        const int f = chunk * 64 + lane;                       // 0..639 = c*5+s
        const float* Wf = p ? Wb_fuse : Wa_fuse;   // [3][256]
        const float* Wt = p ? Wb_tri  : Wa_tri;    // [128][128][5] flat o*640+f
        const float* Wl = p ? Wb_local : Wa_local; // [128][128]
        float a0 = 0.f, a1 = 0.f, a2 = 0.f, a3 = 0.f;
        for (int o = 0; o < C_; o += 4) {
            a0 += Wf[j * 256 + 128 + o]     * Wt[(o)     * 640 + f];
            a1 += Wf[j * 256 + 128 + o + 1] * Wt[(o + 1) * 640 + f];
            a2 += Wf[j * 256 + 128 + o + 2] * Wt[(o + 2) * 640 + f];
            a3 += Wf[j * 256 + 128 + o + 3] * Wt[(o + 3) * 640 + f];
        }
        float acc = (a0 + a1) + (a2 + a3);
        const int s = f % 5, c = f / 5;
        if (s == 0) {   // absorb the local conv into the s=0 slot
            float b0 = 0.f, b1 = 0.f, b2 = 0.f, b3 = 0.f;
            for (int o = 0; o < C_; o += 4) {
                b0 += Wf[j * 256 + o]     * Wl[(o)     * C_ + c];
                b1 += Wf[j * 256 + o + 1] * Wl[(o + 1) * C_ + c];
                b2 += Wf[j * 256 + o + 2] * Wl[(o + 2) * C_ + c];
                b3 += Wf[j * 256 + o + 3] * Wl[(o + 3) * C_ + c];
            }
            acc += (b0 + b1) + (b2 + b3);
        }
        Vw[c * 32 + p * 15 + j * 5 + s] = acc;
    } else {
        if (threadIdx.x < 3) {
            int j = threadIdx.x;
            float acc = ba_fuse[j] + bb_fuse[j];
            for (int o = 0; o < C_; ++o) {
                acc += Wa_fuse[j * 256 + o]       * ba_local[o]
                     + Wa_fuse[j * 256 + 128 + o] * ba_tri[o]
                     + Wb_fuse[j * 256 + o]       * bb_local[o]
                     + Wb_fuse[j * 256 + 128 + o] * bb_tri[o];
            }
            cst[j] = acc;
        }
    }
}

// ---------------------------------------------------------------------------
// Kernel 1: fused gather + features + projection, NATIVE [B,C,E] layout.
// Block = 64 edges; lane = edge. Wave wv handles channels [wv*32, wv*32+32).
// Per channel: 2 coalesced self loads + 8 scattered 4B gathers; weights are
// wave-uniform SGPR broadcasts; per-lane acc[3]; software-pipelined 1 ch deep.
// Final 4-way cross-wave LDS reduce + coalesced stores. 1875 blocks, no tail.
// ---------------------------------------------------------------------------
#define ISSUE(S0,S1,S2,S3,S4,S5,S6,S7,S8,S9) do {                             \
    S0 = ldf(X0, o0); S1 = ldf(X0, o1); S2 = ldf(X0, o2);                     \
    S3 = ldf(X0, o3); S4 = ldf(X0, o4);                                       \
    S5 = ldf(X1, o0); S6 = ldf(X1, o1); S7 = ldf(X1, o2);                     \
    S8 = ldf(X1, o3); S9 = ldf(X1, o4);                                       \
} while (0)

#define ADV() do { o0 += 4u * E_; o1 += 4u * E_; o2 += 4u * E_;               \
                   o3 += 4u * E_; o4 += 4u * E_; } while (0)

#define COMP(S0,S1,S2,S3,S4,S5,S6,S7,S8,S9, cc) do {                          \
    const float* wc = Vw + ((cbase + (cc)) << 5);                             \
    float sa1 = S1 + S3, sa2 = S2 + S4;                                       \
    float da1 = fabsf(S1 - S3), da2 = fabsf(S2 - S4);                         \
    float sb1 = S6 + S8, sb2 = S7 + S9;                                       \
    float db1 = fabsf(S6 - S8), db2 = fabsf(S7 - S9);                         \
    acc0 += wc[0]  * S0 + wc[1]  * sa1 + wc[2]  * sa2 + wc[3]  * da1          \
          + wc[4]  * da2 + wc[15] * S5 + wc[16] * sb1 + wc[17] * sb2          \
          + wc[18] * db1 + wc[19] * db2;                                      \
    acc1 += wc[5]  * S0 + wc[6]  * sa1 + wc[7]  * sa2 + wc[8]  * da1          \
          + wc[9]  * da2 + wc[20] * S5 + wc[21] * sb1 + wc[22] * sb2          \
          + wc[23] * db1 + wc[24] * db2;                                      \
    acc2 += wc[10] * S0 + wc[11] * sa1 + wc[12] * sa2 + wc[13] * da1          \
          + wc[14] * da2 + wc[25] * S5 + wc[26] * sb1 + wc[27] * sb2          \
          + wc[28] * db1 + wc[29] * db2;                                      \
} while (0)

__global__ __launch_bounds__(256, 6) void mesh_native_kernel(
    const float* __restrict__ x0, const float* __restrict__ x1,
    const int* __restrict__ gemm, const float* __restrict__ Vw,
    const float* __restrict__ cst, float* __restrict__ out)
{
    __shared__ float red[4][3][64];
    const int lane  = threadIdx.x & 63;
    const int wvs   = __builtin_amdgcn_readfirstlane(threadIdx.x >> 6); // scalar
    const int ebase = blockIdx.x * 64;
    const int edge  = ebase + lane;          // grid sized exactly: no tail
    const int bb    = (edge >= E_) ? 1 : 0;
    const int e     = edge - (bb ? E_ : 0);
    const float* X0 = x0 + (size_t)bb * (C_ * E_);
    const float* X1 = x1 + (size_t)bb * (C_ * E_);
    const int4 gi   = ((const int4*)gemm)[edge];
    const int cbase = wvs * 32;

    // byte offsets for this wave's first channel
    uint32_ o0 = ((uint32_)cbase * E_ + (uint32_)e)    * 4u;
    uint32_ o1 = ((uint32_)cbase * E_ + (uint32_)gi.x) * 4u;
    uint32_ o2 = ((uint32_)cbase * E_ + (uint32_)gi.y) * 4u;
    uint32_ o3 = ((uint32_)cbase * E_ + (uint32_)gi.z) * 4u;
    uint32_ o4 = ((uint32_)cbase * E_ + (uint32_)gi.w) * 4u;

    float A0, A1, A2, A3, A4, A5, A6, A7, A8, A9;
    float D0, D1, D2, D3, D4, D5, D6, D7, D8, D9;
    float acc0 = 0.f, acc1 = 0.f, acc2 = 0.f;

    ISSUE(A0,A1,A2,A3,A4,A5,A6,A7,A8,A9);   // channel 0
    ADV();
    ISSUE(D0,D1,D2,D3,D4,D5,D6,D7,D8,D9);   // channel 1

#pragma unroll
    for (int c = 0; c < 30; c += 2) {
        COMP(A0,A1,A2,A3,A4,A5,A6,A7,A8,A9, c);
        ADV();
        ISSUE(A0,A1,A2,A3,A4,A5,A6,A7,A8,A9);   // channel c+2
        COMP(D0,D1,D2,D3,D4,D5,D6,D7,D8,D9, c + 1);
        ADV();
        ISSUE(D0,D1,D2,D3,D4,D5,D6,D7,D8,D9);   // channel c+3
    }
    COMP(A0,A1,A2,A3,A4,A5,A6,A7,A8,A9, 30);
    COMP(D0,D1,D2,D3,D4,D5,D6,D7,D8,D9, 31);

    red[wvs][0][lane] = acc0;
    red[wvs][1][lane] = acc1;
    red[wvs][2][lane] = acc2;
    __syncthreads();

    if (threadIdx.x < 192) {
        const int j  = threadIdx.x >> 6;     // 0..2
        const int el = threadIdx.x & 63;
        float v = (red[0][j][el] + red[1][j][el])
                + (red[2][j][el] + red[3][j][el]) + cst[j];
        const int ed  = ebase + el;
        const int bb2 = (ed >= E_) ? 1 : 0;
        const int ee  = ed - (bb2 ? E_ : 0);
        out[(size_t)bb2 * 3 * E_ + (size_t)j * E_ + ee] = v;
    }
}

extern "C" void kernel_launch(void* const* d_in, const int* in_sizes, int n_in,
                              void* d_out, int out_size, void* d_ws, size_t ws_size,
                              hipStream_t stream) {
    const float* x0       = (const float*)d_in[0];
    const float* x1       = (const float*)d_in[1];
    const int*   gemm     = (const int*)d_in[2];
    const float* Wa_local = (const float*)d_in[3];
    const float* ba_local = (const float*)d_in[4];
    const float* Wb_local = (const float*)d_in[5];
    const float* bb_local = (const float*)d_in[6];
    const float* Wa_tri   = (const float*)d_in[7];
    const float* ba_tri   = (const float*)d_in[8];
    const float* Wb_tri   = (const float*)d_in[9];
    const float* bb_tri   = (const float*)d_in[10];
    const float* Wa_fuse  = (const float*)d_in[11];
    const float* ba_fuse  = (const float*)d_in[12];
    const float* Wb_fuse  = (const float*)d_in[13];
    const float* bb_fuse  = (const float*)d_in[14];
    float* out = (float*)d_out;

    float* Vw  = (float*)d_ws;        // 128*32 floats, channel-major
    float* cst = Vw + C_ * 32;        // 3 floats

    hipLaunchKernelGGL(fuse_weights_kernel, dim3(16), dim3(256), 0, stream,
                       Wa_local, ba_local, Wb_local, bb_local,
                       Wa_tri, ba_tri, Wb_tri, bb_tri,
                       Wa_fuse, ba_fuse, Wb_fuse, bb_fuse, Vw, cst);

    hipLaunchKernelGGL(mesh_native_kernel, dim3((B_ * E_) / 64), dim3(256),
                       0, stream, x0, x1, gemm, Vw, cst, out);
}

// Round 9
// 250.033 us; speedup vs baseline: 6.3262x; 6.3262x over previous
//
#include <hip/hip_runtime.h>
#include <hip/hip_bf16.h>
#include <cstdint>

#define B_ 2
#define C_ 128
#define E_ 60000

typedef unsigned int uint32_;
typedef unsigned short ushort_;
typedef float v2f __attribute__((ext_vector_type(2)));

// unpack two bf16 (dword: low = ch0, high = ch1) to packed float2
__device__ __forceinline__ v2f bp2(uint32_ v) {
    v2f r;
    r.x = __uint_as_float(v << 16);
    r.y = __uint_as_float(v & 0xffff0000u);
    return r;
}

__device__ __forceinline__ v2f vabs2(v2f a) {
    v2f r; r.x = fabsf(a.x); r.y = fabsf(a.y); return r;
}

// float -> bf16 round-to-nearest-even
__device__ __forceinline__ ushort_ f2b(float f) {
    union { float f; uint32_ u; } x; x.f = f;
    uint32_ u = x.u + 0x7fffu + ((x.u >> 16) & 1u);
    return (ushort_)(u >> 16);
}

__device__ __forceinline__ uint32_ packb(float lo, float hi) {
    return (uint32_)f2b(lo) | ((uint32_)f2b(hi) << 16);
}

// within-32-lane-group xor-add via ds_swizzle (and_mask 0x1F keeps halves separate)
__device__ __forceinline__ float swz_add(float v, const int pat) {
    switch (pat) {
    case 1:  return v + __int_as_float(__builtin_amdgcn_ds_swizzle(__float_as_int(v), 0x041F));
    case 2:  return v + __int_as_float(__builtin_amdgcn_ds_swizzle(__float_as_int(v), 0x081F));
    case 4:  return v + __int_as_float(__builtin_amdgcn_ds_swizzle(__float_as_int(v), 0x101F));
    case 8:  return v + __int_as_float(__builtin_amdgcn_ds_swizzle(__float_as_int(v), 0x201F));
    default: return v + __int_as_float(__builtin_amdgcn_ds_swizzle(__float_as_int(v), 0x401F));
    }
}

// ---------------------------------------------------------------------------
// Kernel 0: fold the 256->3 fuse conv into per-path weights (wave-parallel).
// s>0  -> Vw[(pj*5+s)*C_ + c]   (pair layout used by mesh kernel, s=1..4)
// s==0 -> Vs[pj*C_ + c]         (plane layout used by transpose self-dot;
//                                absorbs the local conv)
// cst[j] = all bias terms. Grid must be 16 blocks of 256.
// ---------------------------------------------------------------------------
__global__ __launch_bounds__(256) void fuse_weights_kernel(
    const float* __restrict__ Wa_local, const float* __restrict__ ba_local,
    const float* __restrict__ Wb_local, const float* __restrict__ bb_local,
    const float* __restrict__ Wa_tri,  const float* __restrict__ ba_tri,
    const float* __restrict__ Wb_tri,  const float* __restrict__ bb_tri,
    const float* __restrict__ Wa_fuse, const float* __restrict__ ba_fuse,
    const float* __restrict__ Wb_fuse, const float* __restrict__ bb_fuse,
    float* __restrict__ Vw, float* __restrict__ Vs, float* __restrict__ cst)
{
    const int lane = threadIdx.x & 63;
    if (blockIdx.x < 15) {
        const int wid   = blockIdx.x * 4 + (threadIdx.x >> 6); // 0..59
        const int pj    = wid / 10;                            // 0..5
        const int chunk = wid % 10;                            // 0..9
        const int p = pj / 3, j = pj % 3;
        const int f = chunk * 64 + lane;                       // 0..639 = c*5+s
        const float* Wf = p ? Wb_fuse : Wa_fuse;   // [3][256]
        const float* Wt = p ? Wb_tri  : Wa_tri;    // [128][128][5] flat o*640+f
        const float* Wl = p ? Wb_local : Wa_local; // [128][128]
        float a0 = 0.f, a1 = 0.f, a2 = 0.f, a3 = 0.f;
        for (int o = 0; o < C_; o += 4) {
            a0 += Wf[j * 256 + 128 + o]     * Wt[(o)     * 640 + f];
            a1 += Wf[j * 256 + 128 + o + 1] * Wt[(o + 1) * 640 + f];
            a2 += Wf[j * 256 + 128 + o + 2] * Wt[(o + 2) * 640 + f];
            a3 += Wf[j * 256 + 128 + o + 3] * Wt[(o + 3) * 640 + f];
        }
        float acc = (a0 + a1) + (a2 + a3);
        const int s = f % 5, c = f / 5;
        if (s == 0) {   // absorb the local conv into the s=0 slot
            float b0 = 0.f, b1 = 0.f, b2 = 0.f, b3 = 0.f;
            for (int o = 0; o < C_; o += 4) {
                b0 += Wf[j * 256 + o]     * Wl[(o)     * C_ + c];
                b1 += Wf[j * 256 + o + 1] * Wl[(o + 1) * C_ + c];
                b2 += Wf[j * 256 + o + 2] * Wl[(o + 2) * C_ + c];
                b3 += Wf[j * 256 + o + 3] * Wl[(o + 3) * C_ + c];
            }
            acc += (b0 + b1) + (b2 + b3);
            Vs[pj * C_ + c] = acc;
        } else {
            Vw[(pj * 5 + s) * C_ + c] = acc;
        }
    } else {
        if (threadIdx.x < 3) {
            int j = threadIdx.x;
            float acc = ba_fuse[j] + bb_fuse[j];
            for (int o = 0; o < C_; ++o) {
                acc += Wa_fuse[j * 256 + o]       * ba_local[o]
                     + Wa_fuse[j * 256 + 128 + o] * ba_tri[o]
                     + Wb_fuse[j * 256 + o]       * bb_local[o]
                     + Wb_fuse[j * 256 + 128 + o] * bb_tri[o];
            }
            cst[j] = acc;
        }
    }
}

// ---------------------------------------------------------------------------
// Kernel 1: transpose+quantize+SELF-DOT. Tile = 32e x 128c, ONE 16.8 KB LDS
// buffer used twice (x0 pass, then x1 pass) -> 8 blocks/CU. Each 512 B output
// row is written contiguously by 8 adjacent lanes (full HBM lines). While the
// row's 128 channels are in registers, computes psum[b][j][e] = s=0+local term.
// E_/32 = 1875 exact, no tail.
// ---------------------------------------------------------------------------
__global__ __launch_bounds__(256) void transpose_fused_kernel(
    const float* __restrict__ x0, const float* __restrict__ x1,
    uint32_* __restrict__ y, const float* __restrict__ Vs,
    float* __restrict__ psum)
{
    __shared__ float tile[32][131];
    const int b   = blockIdx.y;
    const int e0  = blockIdx.x * 32;
    const int t   = threadIdx.x;
    const int c   = t >> 1;           // 0..127 (load phase)
    const int eh  = (t & 1) * 16;     // 0 or 16
    const int e   = t >> 3;           // 0..31 (extract phase)
    const int k16 = (t & 7) * 16;     // dword offset in 128-dword row

    const float* s0 = x0 + (size_t)b * C_ * E_ + (size_t)c * E_ + e0 + eh;
    const float* s1 = x1 + (size_t)b * C_ * E_ + (size_t)c * E_ + e0 + eh;

    float ra[16], rb[16];

    // ---- pass 1: x0 ----
    {
        float4 v0 = *(const float4*)(s0);
        float4 v1 = *(const float4*)(s0 + 4);
        float4 v2 = *(const float4*)(s0 + 8);
        float4 v3 = *(const float4*)(s0 + 12);
        tile[eh + 0][c] = v0.x;  tile[eh + 1][c] = v0.y;
        tile[eh + 2][c] = v0.z;  tile[eh + 3][c] = v0.w;
        tile[eh + 4][c] = v1.x;  tile[eh + 5][c] = v1.y;
        tile[eh + 6][c] = v1.z;  tile[eh + 7][c] = v1.w;
        tile[eh + 8][c] = v2.x;  tile[eh + 9][c] = v2.y;
        tile[eh + 10][c] = v2.z; tile[eh + 11][c] = v2.w;
        tile[eh + 12][c] = v3.x; tile[eh + 13][c] = v3.y;
        tile[eh + 14][c] = v3.z; tile[eh + 15][c] = v3.w;
    }
    __syncthreads();
#pragma unroll
    for (int i = 0; i < 16; ++i) ra[i] = tile[e][k16 + i];
    __syncthreads();
    // ---- pass 2: x1 ----
    {
        float4 v0 = *(const float4*)(s1);
        float4 v1 = *(const float4*)(s1 + 4);
        float4 v2 = *(const float4*)(s1 + 8);
        float4 v3 = *(const float4*)(s1 + 12);
        tile[eh + 0][c] = v0.x;  tile[eh + 1][c] = v0.y;
        tile[eh + 2][c] = v0.z;  tile[eh + 3][c] = v0.w;
        tile[eh + 4][c] = v1.x;  tile[eh + 5][c] = v1.y;
        tile[eh + 6][c] = v1.z;  tile[eh + 7][c] = v1.w;
        tile[eh + 8][c] = v2.x;  tile[eh + 9][c] = v2.y;
        tile[eh + 10][c] = v2.z; tile[eh + 11][c] = v2.w;
        tile[eh + 12][c] = v3.x; tile[eh + 13][c] = v3.y;
        tile[eh + 14][c] = v3.z; tile[eh + 15][c] = v3.w;
    }
    __syncthreads();
#pragma unroll
    for (int i = 0; i < 16; ++i) rb[i] = tile[e][k16 + i];

    // pack + full-row store: thread covers output dwords [k16, k16+16)
    uint32_* drow = y + (((size_t)(b * E_ + e0 + e)) << 7) + k16;
#pragma unroll
    for (int m = 0; m < 4; ++m) {
        uint4 w_;
        w_.x = packb(ra[4 * m],     ra[4 * m + 1]);
        w_.y = packb(rb[4 * m],     rb[4 * m + 1]);
        w_.z = packb(ra[4 * m + 2], ra[4 * m + 3]);
        w_.w = packb(rb[4 * m + 2], rb[4 * m + 3]);
        *(uint4*)(drow + 4 * m) = w_;
    }

    // self-dot: channels [k16, k16+16) of both paths vs s=0 weight planes
    float p0 = 0.f, p1 = 0.f, p2 = 0.f;
#pragma unroll
    for (int i = 0; i < 16; ++i) {
        const float va = ra[i], vb = rb[i];
        p0 += Vs[0 * C_ + k16 + i] * va + Vs[3 * C_ + k16 + i] * vb;
        p1 += Vs[1 * C_ + k16 + i] * va + Vs[4 * C_ + k16 + i] * vb;
        p2 += Vs[2 * C_ + k16 + i] * va + Vs[5 * C_ + k16 + i] * vb;
    }
    // reduce across the 8 lanes sharing row e (consecutive lanes, xor 1/2/4)
    p0 = swz_add(p0, 1); p0 = swz_add(p0, 2); p0 = swz_add(p0, 4);
    p1 = swz_add(p1, 1); p1 = swz_add(p1, 2); p1 = swz_add(p1, 4);
    p2 = swz_add(p2, 1); p2 = swz_add(p2, 2); p2 = swz_add(p2, 4);
    const int m = t & 7;
    if (m < 3) {
        float v = (m == 0) ? p0 : ((m == 1) ? p1 : p2);
        psum[((size_t)b * 3 + m) * E_ + e0 + e] = v;
    }
}

// ---------------------------------------------------------------------------
// Kernel 2: fused NEIGHBOR gather + features + 3-channel projection.
// Self/local term comes precomputed via psum. Two edges per wave-iteration,
// 8 dwordx2 gathers; 24 named weight registers; ds_swizzle reduce.
// ---------------------------------------------------------------------------
#define LDW(p, j, s) (*(const v2f*)(Vw + ((((p) * 3 + (j)) * 5 + (s)) << 7) + (lane << 1)))

#define EDGE_DOT(P1,P2,P3,P4, R0,R1,R2) do {                                  \
    v2f a1 = bp2(P1.x), a2 = bp2(P2.x), a3 = bp2(P3.x), a4 = bp2(P4.x);       \
    v2f b1 = bp2(P1.y), b2 = bp2(P2.y), b3 = bp2(P3.y), b4 = bp2(P4.y);       \
    v2f sa1 = a1 + a3, sa2 = a2 + a4;                                         \
    v2f da1 = vabs2(a1 - a3), da2 = vabs2(a2 - a4);                           \
    v2f sb1 = b1 + b3, sb2 = b2 + b4;                                         \
    v2f db1 = vabs2(b1 - b3), db2 = vabs2(b2 - b4);                           \
    v2f t0 = w001 * sa1 + w002 * sa2 + w003 * da1 + w004 * da2                \
           + w101 * sb1 + w102 * sb2 + w103 * db1 + w104 * db2;               \
    v2f t1 = w011 * sa1 + w012 * sa2 + w013 * da1 + w014 * da2                \
           + w111 * sb1 + w112 * sb2 + w113 * db1 + w114 * db2;               \
    v2f t2 = w021 * sa1 + w022 * sa2 + w023 * da1 + w024 * da2                \
           + w121 * sb1 + w122 * sb2 + w123 * db1 + w124 * db2;               \
    R0 = t0.x + t0.y; R1 = t1.x + t1.y; R2 = t2.x + t2.y;                     \
} while (0)

__global__ __launch_bounds__(256, 4) void mesh_fused_kernel(
    const uint2* __restrict__ yy, const int* __restrict__ gemm,
    const float* __restrict__ Vw, const float* __restrict__ cst,
    const float* __restrict__ psum, float* __restrict__ out)
{
    const int lane = threadIdx.x & 63;
    const int wv   = threadIdx.x >> 6;
    const int gw   = blockIdx.x * 4 + wv;
    const int nw   = gridDim.x * 4;

    v2f w001 = LDW(0,0,1), w002 = LDW(0,0,2), w003 = LDW(0,0,3), w004 = LDW(0,0,4);
    v2f w011 = LDW(0,1,1), w012 = LDW(0,1,2), w013 = LDW(0,1,3), w014 = LDW(0,1,4);
    v2f w021 = LDW(0,2,1), w022 = LDW(0,2,2), w023 = LDW(0,2,3), w024 = LDW(0,2,4);
    v2f w101 = LDW(1,0,1), w102 = LDW(1,0,2), w103 = LDW(1,0,3), w104 = LDW(1,0,4);
    v2f w111 = LDW(1,1,1), w112 = LDW(1,1,2), w113 = LDW(1,1,3), w114 = LDW(1,1,4);
    v2f w121 = LDW(1,2,1), w122 = LDW(1,2,2), w123 = LDW(1,2,3), w124 = LDW(1,2,4);

    const int  jj     = lane >> 4;                 // 0..3
    const bool is0    = (jj == 0), is1 = (jj == 1);
    const bool writer = ((lane & 15) == 0) && (jj < 3);
    const float cj    = is0 ? cst[0] : (is1 ? cst[1] : cst[2]);
    float* obase      = out + (size_t)(jj < 3 ? jj : 2) * E_;
    const float* pbase = psum + (size_t)(jj < 3 ? jj : 2) * E_;

    const int4* g4 = (const int4*)gemm;
    const int npair = (B_ * E_) / 2;

    int4 giA = make_int4(0, 0, 0, 0), giB = giA;
    if (gw < npair) { giA = g4[2 * gw]; giB = g4[2 * gw + 1]; }

    for (int pair = gw; pair < npair; pair += nw) {
        const int nxt = pair + nw;
        const int4 gA = giA, gB = giB;
        if (nxt < npair) { giA = g4[2 * nxt]; giB = g4[2 * nxt + 1]; }  // prefetch

        const int e0 = 2 * pair;
        const int b  = (e0 >= E_) ? 1 : 0;
        const int e  = e0 - (b ? E_ : 0);
        const uint2* Y = yy + (size_t)b * (E_ * 64);   // row = 64 uint2

        const uint32_ oA1 = ((uint32_)gA.x << 6) + lane;
        const uint32_ oA2 = ((uint32_)gA.y << 6) + lane;
        const uint32_ oA3 = ((uint32_)gA.z << 6) + lane;
        const uint32_ oA4 = ((uint32_)gA.w << 6) + lane;
        const uint32_ oB1 = ((uint32_)gB.x << 6) + lane;
        const uint32_ oB2 = ((uint32_)gB.y << 6) + lane;
        const uint32_ oB3 = ((uint32_)gB.z << 6) + lane;
        const uint32_ oB4 = ((uint32_)gB.w << 6) + lane;

        // 8 independent dwordx2 neighbor gathers
        const uint2 PA1 = Y[oA1], PA2 = Y[oA2], PA3 = Y[oA3], PA4 = Y[oA4];
        const uint2 PB1 = Y[oB1], PB2 = Y[oB2], PB3 = Y[oB3], PB4 = Y[oB4];

        float rA0, rA1, rA2, rB0, rB1, rB2;
        EDGE_DOT(PA1, PA2, PA3, PA4, rA0, rA1, rA2);
        EDGE_DOT(PB1, PB2, PB3, PB4, rB0, rB1, rB2);

        rA0 = swz_add(rA0, 16); rB0 = swz_add(rB0, 16);
        rA1 = swz_add(rA1, 16); rB1 = swz_add(rB1, 16);
        rA2 = swz_add(rA2, 16); rB2 = swz_add(rB2, 16);
        rA0 += __shfl_xor(rA0, 32, 64); rB0 += __shfl_xor(rB0, 32, 64);
        rA1 += __shfl_xor(rA1, 32, 64); rB1 += __shfl_xor(rB1, 32, 64);
        rA2 += __shfl_xor(rA2, 32, 64); rB2 += __shfl_xor(rB2, 32, 64);

        float vA = is0 ? rA0 : (is1 ? rA1 : rA2);
        float vB = is0 ? rB0 : (is1 ? rB1 : rB2);
        vA = swz_add(vA, 1); vB = swz_add(vB, 1);
        vA = swz_add(vA, 2); vB = swz_add(vB, 2);
        vA = swz_add(vA, 4); vB = swz_add(vB, 4);
        vA = swz_add(vA, 8); vB = swz_add(vB, 8);

        if (writer) {
            const float2 ps = *(const float2*)(pbase + (size_t)b * 3 * E_ + e);
            float2 st;
            st.x = vA + cj + ps.x;
            st.y = vB + cj + ps.y;
            *(float2*)(obase + (size_t)b * 3 * E_ + e) = st;   // e even -> aligned
        }
    }
}

extern "C" void kernel_launch(void* const* d_in, const int* in_sizes, int n_in,
                              void* d_out, int out_size, void* d_ws, size_t ws_size,
                              hipStream_t stream) {
    const float* x0       = (const float*)d_in[0];
    const float* x1       = (const float*)d_in[1];
    const int*   gemm     = (const int*)d_in[2];
    const float* Wa_local = (const float*)d_in[3];
    const float* ba_local = (const float*)d_in[4];
    const float* Wb_local = (const float*)d_in[5];
    const float* bb_local = (const float*)d_in[6];
    const float* Wa_tri   = (const float*)d_in[7];
    const float* ba_tri   = (const float*)d_in[8];
    const float* Wb_tri   = (const float*)d_in[9];
    const float* bb_tri   = (const float*)d_in[10];
    const float* Wa_fuse  = (const float*)d_in[11];
    const float* ba_fuse  = (const float*)d_in[12];
    const float* Wb_fuse  = (const float*)d_in[13];
    const float* bb_fuse  = (const float*)d_in[14];
    float* out = (float*)d_out;

    uint32_* y    = (uint32_*)d_ws;                       // B*E*128 dwords
    float*   psum = (float*)(y + (size_t)B_ * E_ * 128);  // B*3*E floats
    float*   Vw   = psum + (size_t)B_ * 3 * E_;           // 3840 floats (s=1..4)
    float*   Vs   = Vw + 2 * 3 * 5 * C_;                  // 768 floats (s=0)
    float*   cst  = Vs + 6 * C_;                          // 3 floats

    hipLaunchKernelGGL(fuse_weights_kernel, dim3(16), dim3(256), 0, stream,
                       Wa_local, ba_local, Wb_local, bb_local,
                       Wa_tri, ba_tri, Wb_tri, bb_tri,
                       Wa_fuse, ba_fuse, Wb_fuse, bb_fuse, Vw, Vs, cst);

    hipLaunchKernelGGL(transpose_fused_kernel, dim3(E_ / 32, B_),
                       dim3(256), 0, stream, x0, x1, y, Vs, psum);

    hipLaunchKernelGGL(mesh_fused_kernel, dim3(2048), dim3(256), 0, stream,
                       (const uint2*)y, gemm, Vw, cst, psum, out);
}